// Round 2
// baseline (515.840 us; speedup 1.0000x reference)
//
#include <hip/hip_runtime.h>
#include <hip/hip_bf16.h>
#include <hip/hip_fp16.h>
#include <math.h>

// Problem constants (fixed by the reference)
#define NN 1024      // proposals
#define DAPP 1024    // appearance dim
#define DK 64        // key dim
#define DG 64        // geo dim
#define NR 16        // relations

typedef __bf16 bf16x8 __attribute__((ext_vector_type(8)));
typedef _Float16 f16x8 __attribute__((ext_vector_type(8)));
typedef _Float16 f16x4 __attribute__((ext_vector_type(4)));
typedef float f32x4 __attribute__((ext_vector_type(4)));

// ---------------- ws layout (bytes) ----------------
static constexpr size_t OFF_FAB = 0;
static constexpr size_t OFF_WB  = OFF_FAB + (size_t)NN * DAPP * 2;
static constexpr size_t OFF_KB  = OFF_WB + (size_t)3 * NR * DK * DAPP * 2;
static constexpr size_t OFF_QB  = OFF_KB + (size_t)NR * NN * DK * 2;
static constexpr size_t OFF_V   = OFF_QB + (size_t)NR * NN * DK * 2;
static constexpr size_t OFF_S   = OFF_V + (size_t)NR * NN * DK * 4;
static constexpr size_t OFF_ST  = OFF_S + (size_t)NR * NN * NN * 2;

// ---------------- K0: cast f_a and W{K,Q,V} to bf16 (x8 vectorized) ----------------
__global__ __launch_bounds__(256) void cast_kernel(
    const float* __restrict__ fa, const float* __restrict__ wk,
    const float* __restrict__ wq, const float* __restrict__ wv,
    __bf16* __restrict__ fab, __bf16* __restrict__ wb) {
  int i8 = (blockIdx.x * 256 + threadIdx.x) * 8;  // 0..4M-1, step 8
  const int M1 = NN * DAPP;                       // 1M (divisible by 8)
  const float* src;
  __bf16* dst;
  int o;
  if (i8 < M1) {
    src = fa; dst = fab; o = i8;
  } else {
    int j = i8 - M1;                              // 0..3M-1
    int p = j >> 20;                              // chunk boundaries are 8-aligned
    o = j & (M1 - 1);
    src = (p == 0) ? wk : ((p == 1) ? wq : wv);
    dst = wb + ((size_t)p << 20);
  }
  float4 a = *(const float4*)(src + o);
  float4 b = *(const float4*)(src + o + 4);
  bf16x8 v;
  v[0] = (__bf16)a.x; v[1] = (__bf16)a.y; v[2] = (__bf16)a.z; v[3] = (__bf16)a.w;
  v[4] = (__bf16)b.x; v[5] = (__bf16)b.y; v[6] = (__bf16)b.z; v[7] = (__bf16)b.w;
  *(bf16x8*)(dst + o) = v;
}

// ---------------- K1: KQV projection, bf16 MFMA, fused bias ----------------
__global__ __launch_bounds__(256) void kqv_kernel(
    const __bf16* __restrict__ fab, const __bf16* __restrict__ wb,
    const float* __restrict__ kbias, const float* __restrict__ qbias,
    const float* __restrict__ vbias,
    __bf16* __restrict__ Kb, __bf16* __restrict__ Qb, float* __restrict__ V) {
  int wave = blockIdx.x * 4 + (threadIdx.x >> 6);  // 0..3071
  int l = threadIdx.x & 63;
  int nt = wave / 96;        // 32 n-tiles
  int jt = wave % 96;        // 96 j-tiles
  int n0 = nt * 32, j0 = jt * 32;
  int ra = l & 15;
  int ko = (l >> 4) * 8;

  f32x4 acc[2][2] = {};
  for (int k0 = 0; k0 < DAPP; k0 += 32) {
    bf16x8 a0 = *(const bf16x8*)(fab + (size_t)(n0 + ra) * DAPP + k0 + ko);
    bf16x8 a1 = *(const bf16x8*)(fab + (size_t)(n0 + 16 + ra) * DAPP + k0 + ko);
    bf16x8 b0 = *(const bf16x8*)(wb + (size_t)(j0 + ra) * DAPP + k0 + ko);
    bf16x8 b1 = *(const bf16x8*)(wb + (size_t)(j0 + 16 + ra) * DAPP + k0 + ko);
    acc[0][0] = __builtin_amdgcn_mfma_f32_16x16x32_bf16(a0, b0, acc[0][0], 0, 0, 0);
    acc[0][1] = __builtin_amdgcn_mfma_f32_16x16x32_bf16(a0, b1, acc[0][1], 0, 0, 0);
    acc[1][0] = __builtin_amdgcn_mfma_f32_16x16x32_bf16(a1, b0, acc[1][0], 0, 0, 0);
    acc[1][1] = __builtin_amdgcn_mfma_f32_16x16x32_bf16(a1, b1, acc[1][1], 0, 0, 0);
  }

  // C/D layout: col = lane&15, row = (lane>>4)*4 + reg
  #pragma unroll
  for (int i = 0; i < 2; i++) {
    #pragma unroll
    for (int jj = 0; jj < 2; jj++) {
      #pragma unroll
      for (int q = 0; q < 4; q++) {
        int n = n0 + i * 16 + (l >> 4) * 4 + q;
        int col = j0 + jj * 16 + (l & 15);
        int proj = col >> 10;
        int rd = col & 1023;          // r*64 + d
        int r = rd >> 6, d = rd & 63;
        float v = acc[i][jj][q];
        size_t oidx = ((size_t)r * NN + n) * DK + d;
        if (proj == 0)      Kb[oidx] = (__bf16)(v + kbias[rd]);
        else if (proj == 1) Qb[oidx] = (__bf16)(v + qbias[rd]);
        else                V[oidx] = v + vbias[rd];
      }
    }
  }
}

// ---------------- K2: FUSED gate(MFMA) + scores -> X (fp16) ----------------
// One independent wave-job per 16n x 16m tile (all 16 r). 4096 jobs =
// 1024 blocks x 4 waves, NO barriers.
__global__ __launch_bounds__(256) void gate_score_kernel(
    const float* __restrict__ pe, const float* __restrict__ WGw,
    const float* __restrict__ WGb,
    const __bf16* __restrict__ Kb, const __bf16* __restrict__ Qb,
    _Float16* __restrict__ X) {
  // per-wave lg slice: [r][n][m], n padded to 17, m padded to 20
  __shared__ alignas(16) _Float16 lg[4][16][17][20];
  int t = threadIdx.x;
  int l = t & 63, w = t >> 6;
  int job = blockIdx.x * 4 + w;
  int nt = job >> 6, mt = job & 63;
  int n0 = nt * 16, m0 = mt * 16;
  int pr = l & 15;            // A-row / B-col selector
  int kg = (l >> 4) * 8;      // k-offset within frag
  int mq = (l >> 4) << 2;     // D row quad base

  // WG B-frags (fp32 -> bf16), col = r = pr
  bf16x8 wgf[2];
  #pragma unroll
  for (int f = 0; f < 2; f++) {
    const float* wp = WGw + pr * DG + f * 32 + kg;
    float4 a = *(const float4*)wp;
    float4 b = *(const float4*)(wp + 4);
    bf16x8 v;
    v[0] = (__bf16)a.x; v[1] = (__bf16)a.y; v[2] = (__bf16)a.z; v[3] = (__bf16)a.w;
    v[4] = (__bf16)b.x; v[5] = (__bf16)b.y; v[6] = (__bf16)b.z; v[7] = (__bf16)b.w;
    wgf[f] = v;
  }
  float biasr = WGb[pr];

  // ---- gate: 16 n, 2 MFMA each ----
  #pragma unroll 4
  for (int nl = 0; nl < 16; nl++) {
    const float* pp = pe + (((size_t)(n0 + nl) << 10) + m0 + pr) * DG + kg;
    f32x4 acc = {};
    #pragma unroll
    for (int f = 0; f < 2; f++) {
      float4 a = *(const float4*)(pp + f * 32);
      float4 b = *(const float4*)(pp + f * 32 + 4);
      bf16x8 av;
      av[0] = (__bf16)a.x; av[1] = (__bf16)a.y; av[2] = (__bf16)a.z; av[3] = (__bf16)a.w;
      av[4] = (__bf16)b.x; av[5] = (__bf16)b.y; av[6] = (__bf16)b.z; av[7] = (__bf16)b.w;
      acc = __builtin_amdgcn_mfma_f32_16x16x32_bf16(av, wgf[f], acc, 0, 0, 0);
    }
    // D: col = r = pr, row = m-local = mq + q
    f16x4 ov;
    #pragma unroll
    for (int q = 0; q < 4; q++)
      ov[q] = (_Float16)__logf(fmaxf(acc[q] + biasr, 1e-6f));
    *(f16x4*)&lg[w][pr][nl][mq] = ov;
  }

  // ---- score: 16 r, 2 MFMA each; combine with lg; store X ----
  #pragma unroll 4
  for (int r = 0; r < 16; r++) {
    const __bf16* Kr = Kb + (((size_t)r << 10)) * DK;
    const __bf16* Qr = Qb + (((size_t)r << 10)) * DK;
    f32x4 acc = {};
    #pragma unroll
    for (int f = 0; f < 2; f++) {
      bf16x8 qa = *(const bf16x8*)(Qr + (size_t)(m0 + pr) * DK + f * 32 + kg);
      bf16x8 kb = *(const bf16x8*)(Kr + (size_t)(n0 + pr) * DK + f * 32 + kg);
      acc = __builtin_amdgcn_mfma_f32_16x16x32_bf16(qa, kb, acc, 0, 0, 0);
    }
    // D: col = n-local = pr, row = m-local = mq + q
    f16x4 lgv = *(const f16x4*)&lg[w][r][pr][mq];
    f16x4 xv;
    #pragma unroll
    for (int q = 0; q < 4; q++)
      xv[q] = (_Float16)(acc[q] * 0.125f + (float)lgv[q]);
    *(f16x4*)(X + ((size_t)r << 20) + ((size_t)(n0 + pr) << 10) + m0 + mq) = xv;
  }
}

// ---------------- K3: per-(r,n) row max and sum-exp over X ----------------
__global__ __launch_bounds__(256) void stats_kernel(
    const _Float16* __restrict__ X, float2* __restrict__ stats) {
  int row = blockIdx.x * 4 + (threadIdx.x >> 6);  // 0..16383 = r*1024+n
  int l = threadIdx.x & 63;
  const f16x8* Sp = (const f16x8*)(X + ((size_t)row << 10) + l * 16);
  f16x8 a = Sp[0], b = Sp[1];
  float v[16];
  float mx = -1e30f;
  #pragma unroll
  for (int i = 0; i < 8; i++) { v[i] = (float)a[i]; v[8 + i] = (float)b[i]; }
  #pragma unroll
  for (int i = 0; i < 16; i++) mx = fmaxf(mx, v[i]);
  #pragma unroll
  for (int off = 32; off >= 1; off >>= 1) mx = fmaxf(mx, __shfl_xor(mx, off, 64));
  float sm = 0.f;
  #pragma unroll
  for (int i = 0; i < 16; i++) sm += __expf(v[i] - mx);
  #pragma unroll
  for (int off = 32; off >= 1; off >>= 1) sm += __shfl_xor(sm, off, 64);
  if (l == 0) stats[row] = make_float2(mx, sm);
}

// ---------------- K4: out[n, r*64+d] = sum_m softmax * V[r,m,d] + f_a ----------------
__global__ __launch_bounds__(256) void pv_kernel(
    const _Float16* __restrict__ S, const float2* __restrict__ stats,
    const float* __restrict__ V, const float* __restrict__ fa,
    float* __restrict__ out) {
  int r = blockIdx.x >> 5;
  int n0 = (blockIdx.x & 31) * 32;
  __shared__ float Pt[64][36];   // [m_local][n_local], padded
  __shared__ float Vt[64][68];   // [m_local][d], padded
  __shared__ float2 st[32];
  int t = threadIdx.x;
  if (t < 32) st[t] = stats[r * NN + n0 + t];

  int d0 = (t & 15) * 4;
  int nl0 = (t >> 4) * 2;
  float acc[2][4] = {};

  for (int m0 = 0; m0 < NN; m0 += 64) {
    __syncthreads();
    {
      int nl = t >> 3;
      int ml = (t & 7) * 8;
      const _Float16* sp = S + ((size_t)r << 20) + ((size_t)(n0 + nl) << 10) + m0 + ml;
      f16x8 sv = *(const f16x8*)sp;
      float mxn = st[nl].x;
      #pragma unroll
      for (int u = 0; u < 8; u++) Pt[ml + u][nl] = __expf((float)sv[u] - mxn);
    }
    {
      int ml = t >> 2;
      int dq = (t & 3) * 16;
      const float* vp = V + ((size_t)r * NN + m0 + ml) * DK + dq;
      #pragma unroll
      for (int u = 0; u < 4; u++) {
        float4 vv = ((const float4*)vp)[u];
        *(float4*)&Vt[ml][dq + u * 4] = vv;
      }
    }
    __syncthreads();
    #pragma unroll 8
    for (int ml = 0; ml < 64; ml++) {
      float a0 = Pt[ml][nl0];
      float a1 = Pt[ml][nl0 + 1];
      float4 vv = *(const float4*)&Vt[ml][d0];
      acc[0][0] += a0 * vv.x; acc[0][1] += a0 * vv.y;
      acc[0][2] += a0 * vv.z; acc[0][3] += a0 * vv.w;
      acc[1][0] += a1 * vv.x; acc[1][1] += a1 * vv.y;
      acc[1][2] += a1 * vv.z; acc[1][3] += a1 * vv.w;
    }
  }

  #pragma unroll
  for (int i = 0; i < 2; i++) {
    int n = n0 + nl0 + i;
    float rs = 1.0f / st[nl0 + i].y;
    int col = r * DK + d0;
    const float4 f = *(const float4*)(fa + (size_t)n * DAPP + col);
    float4 o;
    o.x = acc[i][0] * rs + f.x;
    o.y = acc[i][1] * rs + f.y;
    o.z = acc[i][2] * rs + f.z;
    o.w = acc[i][3] * rs + f.w;
    *(float4*)(out + (size_t)n * DAPP + col) = o;
  }
}

// ---------------- launch ----------------
extern "C" void kernel_launch(void* const* d_in, const int* in_sizes, int n_in,
                              void* d_out, int out_size, void* d_ws, size_t ws_size,
                              hipStream_t stream) {
  const float* fa  = (const float*)d_in[0];
  const float* pe  = (const float*)d_in[1];
  const float* WGw = (const float*)d_in[2];
  const float* WGb = (const float*)d_in[3];
  const float* WKw = (const float*)d_in[4];
  const float* WKb = (const float*)d_in[5];
  const float* WQw = (const float*)d_in[6];
  const float* WQb = (const float*)d_in[7];
  const float* WVw = (const float*)d_in[8];
  const float* WVb = (const float*)d_in[9];
  float* out = (float*)d_out;

  char* ws = (char*)d_ws;
  __bf16* fab = (__bf16*)(ws + OFF_FAB);
  __bf16* wb  = (__bf16*)(ws + OFF_WB);
  __bf16* Kb  = (__bf16*)(ws + OFF_KB);
  __bf16* Qb  = (__bf16*)(ws + OFF_QB);
  float*  V   = (float*)(ws + OFF_V);
  _Float16* X = (_Float16*)(ws + OFF_S);
  float2* st  = (float2*)(ws + OFF_ST);

  // K0: cast (4M elems, 8/thread)
  cast_kernel<<<2048, 256, 0, stream>>>(fa, WKw, WQw, WVw, fab, wb);
  // K1: KQV projection
  kqv_kernel<<<768, 256, 0, stream>>>(fab, wb, WKb, WQb, WVb, Kb, Qb, V);
  // K2: fused MFMA-gate + scores -> X  (4096 wave-jobs, 1024 blocks)
  gate_score_kernel<<<1024, 256, 0, stream>>>(pe, WGw, WGb, Kb, Qb, X);
  // K3: stats (16384 rows, 4/block)
  stats_kernel<<<4096, 256, 0, stream>>>(X, st);
  // K4: PV + residual
  pv_kernel<<<512, 256, 0, stream>>>(X, st, V, fa, out);
}

// Round 5
// 486.410 us; speedup vs baseline: 1.0605x; 1.0605x over previous
//
#include <hip/hip_runtime.h>
#include <hip/hip_bf16.h>
#include <hip/hip_fp16.h>
#include <math.h>

// Problem constants (fixed by the reference)
#define NN 1024      // proposals
#define DAPP 1024    // appearance dim
#define DK 64        // key dim
#define DG 64        // geo dim
#define NR 16        // relations

typedef __bf16 bf16x8 __attribute__((ext_vector_type(8)));
typedef _Float16 f16x8 __attribute__((ext_vector_type(8)));
typedef _Float16 f16x4 __attribute__((ext_vector_type(4)));
typedef float f32x4 __attribute__((ext_vector_type(4)));

// ---------------- ws layout (bytes) ----------------
static constexpr size_t OFF_FAB = 0;
static constexpr size_t OFF_WB  = OFF_FAB + (size_t)NN * DAPP * 2;
static constexpr size_t OFF_KB  = OFF_WB + (size_t)3 * NR * DK * DAPP * 2;
static constexpr size_t OFF_QB  = OFF_KB + (size_t)NR * NN * DK * 2;
static constexpr size_t OFF_V   = OFF_QB + (size_t)NR * NN * DK * 2;
static constexpr size_t OFF_S   = OFF_V + (size_t)NR * NN * DK * 2;   // Vt is bf16
static constexpr size_t OFF_ST  = OFF_S + (size_t)NR * NN * NN * 2;

// ---------------- K0: cast f_a and W{K,Q,V} to bf16 (x8 vectorized) ----------------
__global__ __launch_bounds__(256) void cast_kernel(
    const float* __restrict__ fa, const float* __restrict__ wk,
    const float* __restrict__ wq, const float* __restrict__ wv,
    __bf16* __restrict__ fab, __bf16* __restrict__ wb) {
  int i8 = (blockIdx.x * 256 + threadIdx.x) * 8;  // 0..4M-1, step 8
  const int M1 = NN * DAPP;                       // 1M (divisible by 8)
  const float* src;
  __bf16* dst;
  int o;
  if (i8 < M1) {
    src = fa; dst = fab; o = i8;
  } else {
    int j = i8 - M1;                              // 0..3M-1
    int p = j >> 20;                              // chunk boundaries are 8-aligned
    o = j & (M1 - 1);
    src = (p == 0) ? wk : ((p == 1) ? wq : wv);
    dst = wb + ((size_t)p << 20);
  }
  float4 a = *(const float4*)(src + o);
  float4 b = *(const float4*)(src + o + 4);
  bf16x8 v;
  v[0] = (__bf16)a.x; v[1] = (__bf16)a.y; v[2] = (__bf16)a.z; v[3] = (__bf16)a.w;
  v[4] = (__bf16)b.x; v[5] = (__bf16)b.y; v[6] = (__bf16)b.z; v[7] = (__bf16)b.w;
  *(bf16x8*)(dst + o) = v;
}

// ---------------- K1: KQV projection, bf16 MFMA, fused bias ----------------
// V output TRANSPOSED bf16: Vt[r][d][m], so K4 loads V MFMA B-fragments as
// contiguous 16B/lane along m.
__global__ __launch_bounds__(256) void kqv_kernel(
    const __bf16* __restrict__ fab, const __bf16* __restrict__ wb,
    const float* __restrict__ kbias, const float* __restrict__ qbias,
    const float* __restrict__ vbias,
    __bf16* __restrict__ Kb, __bf16* __restrict__ Qb, __bf16* __restrict__ Vt) {
  int wave = blockIdx.x * 4 + (threadIdx.x >> 6);  // 0..3071
  int l = threadIdx.x & 63;
  int nt = wave / 96;        // 32 n-tiles
  int jt = wave % 96;        // 96 j-tiles
  int n0 = nt * 32, j0 = jt * 32;
  int ra = l & 15;
  int ko = (l >> 4) * 8;

  f32x4 acc[2][2] = {};
  for (int k0 = 0; k0 < DAPP; k0 += 32) {
    bf16x8 a0 = *(const bf16x8*)(fab + (size_t)(n0 + ra) * DAPP + k0 + ko);
    bf16x8 a1 = *(const bf16x8*)(fab + (size_t)(n0 + 16 + ra) * DAPP + k0 + ko);
    bf16x8 b0 = *(const bf16x8*)(wb + (size_t)(j0 + ra) * DAPP + k0 + ko);
    bf16x8 b1 = *(const bf16x8*)(wb + (size_t)(j0 + 16 + ra) * DAPP + k0 + ko);
    acc[0][0] = __builtin_amdgcn_mfma_f32_16x16x32_bf16(a0, b0, acc[0][0], 0, 0, 0);
    acc[0][1] = __builtin_amdgcn_mfma_f32_16x16x32_bf16(a0, b1, acc[0][1], 0, 0, 0);
    acc[1][0] = __builtin_amdgcn_mfma_f32_16x16x32_bf16(a1, b0, acc[1][0], 0, 0, 0);
    acc[1][1] = __builtin_amdgcn_mfma_f32_16x16x32_bf16(a1, b1, acc[1][1], 0, 0, 0);
  }

  // C/D layout: col = lane&15, row = (lane>>4)*4 + reg
  #pragma unroll
  for (int i = 0; i < 2; i++) {
    #pragma unroll
    for (int jj = 0; jj < 2; jj++) {
      #pragma unroll
      for (int q = 0; q < 4; q++) {
        int n = n0 + i * 16 + (l >> 4) * 4 + q;
        int col = j0 + jj * 16 + (l & 15);
        int proj = col >> 10;
        int rd = col & 1023;          // r*64 + d
        float v = acc[i][jj][q];
        if (proj == 0) {
          Kb[((size_t)(rd >> 6) * NN + n) * DK + (rd & 63)] = (__bf16)(v + kbias[rd]);
        } else if (proj == 1) {
          Qb[((size_t)(rd >> 6) * NN + n) * DK + (rd & 63)] = (__bf16)(v + qbias[rd]);
        } else {
          Vt[(size_t)rd * NN + n] = (__bf16)(v + vbias[rd]);   // [r][d][m=n]
        }
      }
    }
  }
}

// ---------------- K2: FUSED gate(MFMA) + scores -> X (fp16) ----------------
// One independent wave-job per 16n x 16m tile (all 16 r). 4096 jobs =
// 1024 blocks x 4 waves, NO barriers.
__global__ __launch_bounds__(256) void gate_score_kernel(
    const float* __restrict__ pe, const float* __restrict__ WGw,
    const float* __restrict__ WGb,
    const __bf16* __restrict__ Kb, const __bf16* __restrict__ Qb,
    _Float16* __restrict__ X) {
  // per-wave lg slice: [r][n][m], n padded to 17, m padded to 20
  __shared__ alignas(16) _Float16 lg[4][16][17][20];
  int t = threadIdx.x;
  int l = t & 63, w = t >> 6;
  int job = blockIdx.x * 4 + w;
  int nt = job >> 6, mt = job & 63;
  int n0 = nt * 16, m0 = mt * 16;
  int pr = l & 15;            // A-row / B-col selector
  int kg = (l >> 4) * 8;      // k-offset within frag
  int mq = (l >> 4) << 2;     // D row quad base

  // WG B-frags (fp32 -> bf16), col = r = pr
  bf16x8 wgf[2];
  #pragma unroll
  for (int f = 0; f < 2; f++) {
    const float* wp = WGw + pr * DG + f * 32 + kg;
    float4 a = *(const float4*)wp;
    float4 b = *(const float4*)(wp + 4);
    bf16x8 v;
    v[0] = (__bf16)a.x; v[1] = (__bf16)a.y; v[2] = (__bf16)a.z; v[3] = (__bf16)a.w;
    v[4] = (__bf16)b.x; v[5] = (__bf16)b.y; v[6] = (__bf16)b.z; v[7] = (__bf16)b.w;
    wgf[f] = v;
  }
  float biasr = WGb[pr];

  // ---- gate: 16 n, 2 MFMA each ----
  #pragma unroll 4
  for (int nl = 0; nl < 16; nl++) {
    const float* pp = pe + (((size_t)(n0 + nl) << 10) + m0 + pr) * DG + kg;
    f32x4 acc = {};
    #pragma unroll
    for (int f = 0; f < 2; f++) {
      float4 a = *(const float4*)(pp + f * 32);
      float4 b = *(const float4*)(pp + f * 32 + 4);
      bf16x8 av;
      av[0] = (__bf16)a.x; av[1] = (__bf16)a.y; av[2] = (__bf16)a.z; av[3] = (__bf16)a.w;
      av[4] = (__bf16)b.x; av[5] = (__bf16)b.y; av[6] = (__bf16)b.z; av[7] = (__bf16)b.w;
      acc = __builtin_amdgcn_mfma_f32_16x16x32_bf16(av, wgf[f], acc, 0, 0, 0);
    }
    // D: col = r = pr, row = m-local = mq + q
    f16x4 ov;
    #pragma unroll
    for (int q = 0; q < 4; q++)
      ov[q] = (_Float16)__logf(fmaxf(acc[q] + biasr, 1e-6f));
    *(f16x4*)&lg[w][pr][nl][mq] = ov;
  }

  // ---- score: 16 r, 2 MFMA each; combine with lg; store X ----
  #pragma unroll 4
  for (int r = 0; r < 16; r++) {
    const __bf16* Kr = Kb + (((size_t)r << 10)) * DK;
    const __bf16* Qr = Qb + (((size_t)r << 10)) * DK;
    f32x4 acc = {};
    #pragma unroll
    for (int f = 0; f < 2; f++) {
      bf16x8 qa = *(const bf16x8*)(Qr + (size_t)(m0 + pr) * DK + f * 32 + kg);
      bf16x8 kb = *(const bf16x8*)(Kr + (size_t)(n0 + pr) * DK + f * 32 + kg);
      acc = __builtin_amdgcn_mfma_f32_16x16x32_bf16(qa, kb, acc, 0, 0, 0);
    }
    // D: col = n-local = pr, row = m-local = mq + q
    f16x4 lgv = *(const f16x4*)&lg[w][r][pr][mq];
    f16x4 xv;
    #pragma unroll
    for (int q = 0; q < 4; q++)
      xv[q] = (_Float16)(acc[q] * 0.125f + (float)lgv[q]);
    *(f16x4*)(X + ((size_t)r << 20) + ((size_t)(n0 + pr) << 10) + m0 + mq) = xv;
  }
}

// ---------------- K3: per-(r,n) row max and sum-exp over X ----------------
__global__ __launch_bounds__(256) void stats_kernel(
    const _Float16* __restrict__ X, float2* __restrict__ stats) {
  int row = blockIdx.x * 4 + (threadIdx.x >> 6);  // 0..16383 = r*1024+n
  int l = threadIdx.x & 63;
  const f16x8* Sp = (const f16x8*)(X + ((size_t)row << 10) + l * 16);
  f16x8 a = Sp[0], b = Sp[1];
  float v[16];
  float mx = -1e30f;
  #pragma unroll
  for (int i = 0; i < 8; i++) { v[i] = (float)a[i]; v[8 + i] = (float)b[i]; }
  #pragma unroll
  for (int i = 0; i < 16; i++) mx = fmaxf(mx, v[i]);
  #pragma unroll
  for (int off = 32; off >= 1; off >>= 1) mx = fmaxf(mx, __shfl_xor(mx, off, 64));
  float sm = 0.f;
  #pragma unroll
  for (int i = 0; i < 16; i++) sm += __expf(v[i] - mx);
  #pragma unroll
  for (int off = 32; off >= 1; off >>= 1) sm += __shfl_xor(sm, off, 64);
  if (l == 0) stats[row] = make_float2(mx, sm);
}

// ---------------- K4: MFMA PV + residual (1 wave per job, no LDS/sync) ----------------
// Job = (r, 16-row n-tile, 32-col d-half). 2048 wave-jobs = 512 blocks x 4.
// Each wave: full m loop (32 k-steps), A-frag = exp(X-mx) in bf16 built
// in-register, B-frag = Vt[r][d][m] contiguous 16B loads, 2 MFMAs/step.
// exp argument clamped to <=0 (mathematical invariant: X <= row max).
__global__ __launch_bounds__(256) void pv_kernel(
    const _Float16* __restrict__ X, const float2* __restrict__ stats,
    const __bf16* __restrict__ Vt, const float* __restrict__ fa,
    float* __restrict__ out) {
  int t = threadIdx.x;
  int l = t & 63, w = t >> 6;
  int job = blockIdx.x * 4 + w;      // 0..2047
  int dh = job & 1;                  // d-half: 0 -> d 0..31, 1 -> d 32..63
  int jj = job >> 1;                 // 0..1023
  int r = jj >> 6;
  int n0 = (jj & 63) * 16;
  int pr = l & 15;                   // A-row (n-local) / B-col (d-local)
  int kg = (l >> 4) * 8;             // k-chunk within 32-wide window

  float mxl = stats[r * NN + n0 + pr].x;
  const _Float16* Xrow = X + ((size_t)r << 20) + ((size_t)(n0 + pr) << 10);
  const __bf16* V0 = Vt + (size_t)(r * DK + dh * 32) * NN;

  f32x4 acc[2] = {};
  #pragma unroll 2
  for (int k0 = 0; k0 < NN; k0 += 32) {
    f16x8 xv = *(const f16x8*)(Xrow + k0 + kg);
    bf16x8 pa;
    #pragma unroll
    for (int jq = 0; jq < 8; jq++)
      pa[jq] = (__bf16)__expf(fminf((float)xv[jq] - mxl, 0.0f));
    #pragma unroll
    for (int dt = 0; dt < 2; dt++) {
      bf16x8 vb = *(const bf16x8*)(V0 + (size_t)(dt * 16 + pr) * NN + k0 + kg);
      acc[dt] = __builtin_amdgcn_mfma_f32_16x16x32_bf16(pa, vb, acc[dt], 0, 0, 0);
    }
  }

  // D layout: row(n-local) = (l>>4)*4+q, col(d-local) = pr
  #pragma unroll
  for (int q = 0; q < 4; q++) {
    int n = n0 + (l >> 4) * 4 + q;
    float rs = 1.0f / stats[r * NN + n].y;
    #pragma unroll
    for (int dt = 0; dt < 2; dt++) {
      int col = r * DK + dh * 32 + dt * 16 + pr;
      out[(size_t)n * DAPP + col] = acc[dt][q] * rs + fa[(size_t)n * DAPP + col];
    }
  }
}

// ---------------- launch ----------------
extern "C" void kernel_launch(void* const* d_in, const int* in_sizes, int n_in,
                              void* d_out, int out_size, void* d_ws, size_t ws_size,
                              hipStream_t stream) {
  const float* fa  = (const float*)d_in[0];
  const float* pe  = (const float*)d_in[1];
  const float* WGw = (const float*)d_in[2];
  const float* WGb = (const float*)d_in[3];
  const float* WKw = (const float*)d_in[4];
  const float* WKb = (const float*)d_in[5];
  const float* WQw = (const float*)d_in[6];
  const float* WQb = (const float*)d_in[7];
  const float* WVw = (const float*)d_in[8];
  const float* WVb = (const float*)d_in[9];
  float* out = (float*)d_out;

  char* ws = (char*)d_ws;
  __bf16* fab = (__bf16*)(ws + OFF_FAB);
  __bf16* wb  = (__bf16*)(ws + OFF_WB);
  __bf16* Kb  = (__bf16*)(ws + OFF_KB);
  __bf16* Qb  = (__bf16*)(ws + OFF_QB);
  __bf16* Vt  = (__bf16*)(ws + OFF_V);
  _Float16* X = (_Float16*)(ws + OFF_S);
  float2* st  = (float2*)(ws + OFF_ST);

  // K0: cast (4M elems, 8/thread)
  cast_kernel<<<2048, 256, 0, stream>>>(fa, WKw, WQw, WVw, fab, wb);
  // K1: KQV projection (V transposed bf16)
  kqv_kernel<<<768, 256, 0, stream>>>(fab, wb, WKb, WQb, WVb, Kb, Qb, Vt);
  // K2: fused MFMA-gate + scores -> X  (4096 wave-jobs, 1024 blocks)
  gate_score_kernel<<<1024, 256, 0, stream>>>(pe, WGw, WGb, Kb, Qb, X);
  // K3: stats (16384 rows, 4/block)
  stats_kernel<<<4096, 256, 0, stream>>>(X, st);
  // K4: MFMA PV + residual (2048 wave-jobs, 512 blocks)
  pv_kernel<<<512, 256, 0, stream>>>(X, st, Vt, fa, out);
}

// Round 6
// 478.582 us; speedup vs baseline: 1.0779x; 1.0164x over previous
//
#include <hip/hip_runtime.h>
#include <hip/hip_bf16.h>
#include <hip/hip_fp16.h>
#include <math.h>

// Problem constants (fixed by the reference)
#define NN 1024      // proposals
#define DAPP 1024    // appearance dim
#define DK 64        // key dim
#define DG 64        // geo dim
#define NR 16        // relations

typedef __bf16 bf16x8 __attribute__((ext_vector_type(8)));
typedef _Float16 f16x8 __attribute__((ext_vector_type(8)));
typedef _Float16 f16x4 __attribute__((ext_vector_type(4)));
typedef float f32x4 __attribute__((ext_vector_type(4)));

// ---------------- ws layout (bytes) ----------------
static constexpr size_t OFF_FAB = 0;
static constexpr size_t OFF_WB  = OFF_FAB + (size_t)NN * DAPP * 2;
static constexpr size_t OFF_KB  = OFF_WB + (size_t)3 * NR * DK * DAPP * 2;
static constexpr size_t OFF_QB  = OFF_KB + (size_t)NR * NN * DK * 2;
static constexpr size_t OFF_V   = OFF_QB + (size_t)NR * NN * DK * 2;
static constexpr size_t OFF_S   = OFF_V + (size_t)NR * NN * DK * 2;   // Vt is bf16
static constexpr size_t OFF_ST  = OFF_S + (size_t)NR * NN * NN * 2;

// ---------------- K0: cast f_a and W{K,Q,V} to bf16 (x8 vectorized) ----------------
__global__ __launch_bounds__(256) void cast_kernel(
    const float* __restrict__ fa, const float* __restrict__ wk,
    const float* __restrict__ wq, const float* __restrict__ wv,
    __bf16* __restrict__ fab, __bf16* __restrict__ wb) {
  int i8 = (blockIdx.x * 256 + threadIdx.x) * 8;  // 0..4M-1, step 8
  const int M1 = NN * DAPP;                       // 1M (divisible by 8)
  const float* src;
  __bf16* dst;
  int o;
  if (i8 < M1) {
    src = fa; dst = fab; o = i8;
  } else {
    int j = i8 - M1;                              // 0..3M-1
    int p = j >> 20;                              // chunk boundaries are 8-aligned
    o = j & (M1 - 1);
    src = (p == 0) ? wk : ((p == 1) ? wq : wv);
    dst = wb + ((size_t)p << 20);
  }
  float4 a = *(const float4*)(src + o);
  float4 b = *(const float4*)(src + o + 4);
  bf16x8 v;
  v[0] = (__bf16)a.x; v[1] = (__bf16)a.y; v[2] = (__bf16)a.z; v[3] = (__bf16)a.w;
  v[4] = (__bf16)b.x; v[5] = (__bf16)b.y; v[6] = (__bf16)b.z; v[7] = (__bf16)b.w;
  *(bf16x8*)(dst + o) = v;
}

// ---------------- K1: KQV projection, bf16 MFMA, fused bias ----------------
// V output TRANSPOSED bf16: Vt[r][d][m], so K4 loads V MFMA B-fragments as
// contiguous 16B/lane along m.
__global__ __launch_bounds__(256) void kqv_kernel(
    const __bf16* __restrict__ fab, const __bf16* __restrict__ wb,
    const float* __restrict__ kbias, const float* __restrict__ qbias,
    const float* __restrict__ vbias,
    __bf16* __restrict__ Kb, __bf16* __restrict__ Qb, __bf16* __restrict__ Vt) {
  int wave = blockIdx.x * 4 + (threadIdx.x >> 6);  // 0..3071
  int l = threadIdx.x & 63;
  int nt = wave / 96;        // 32 n-tiles
  int jt = wave % 96;        // 96 j-tiles
  int n0 = nt * 32, j0 = jt * 32;
  int ra = l & 15;
  int ko = (l >> 4) * 8;

  f32x4 acc[2][2] = {};
  for (int k0 = 0; k0 < DAPP; k0 += 32) {
    bf16x8 a0 = *(const bf16x8*)(fab + (size_t)(n0 + ra) * DAPP + k0 + ko);
    bf16x8 a1 = *(const bf16x8*)(fab + (size_t)(n0 + 16 + ra) * DAPP + k0 + ko);
    bf16x8 b0 = *(const bf16x8*)(wb + (size_t)(j0 + ra) * DAPP + k0 + ko);
    bf16x8 b1 = *(const bf16x8*)(wb + (size_t)(j0 + 16 + ra) * DAPP + k0 + ko);
    acc[0][0] = __builtin_amdgcn_mfma_f32_16x16x32_bf16(a0, b0, acc[0][0], 0, 0, 0);
    acc[0][1] = __builtin_amdgcn_mfma_f32_16x16x32_bf16(a0, b1, acc[0][1], 0, 0, 0);
    acc[1][0] = __builtin_amdgcn_mfma_f32_16x16x32_bf16(a1, b0, acc[1][0], 0, 0, 0);
    acc[1][1] = __builtin_amdgcn_mfma_f32_16x16x32_bf16(a1, b1, acc[1][1], 0, 0, 0);
  }

  // C/D layout: col = lane&15, row = (lane>>4)*4 + reg
  #pragma unroll
  for (int i = 0; i < 2; i++) {
    #pragma unroll
    for (int jj = 0; jj < 2; jj++) {
      #pragma unroll
      for (int q = 0; q < 4; q++) {
        int n = n0 + i * 16 + (l >> 4) * 4 + q;
        int col = j0 + jj * 16 + (l & 15);
        int proj = col >> 10;
        int rd = col & 1023;          // r*64 + d
        float v = acc[i][jj][q];
        if (proj == 0) {
          Kb[((size_t)(rd >> 6) * NN + n) * DK + (rd & 63)] = (__bf16)(v + kbias[rd]);
        } else if (proj == 1) {
          Qb[((size_t)(rd >> 6) * NN + n) * DK + (rd & 63)] = (__bf16)(v + qbias[rd]);
        } else {
          Vt[(size_t)rd * NN + n] = (__bf16)(v + vbias[rd]);   // [r][d][m=n]
        }
      }
    }
  }
}

// ---------------- K2: FUSED gate(MFMA) + scores -> X (fp16) ----------------
// One independent wave-job per 16n x 16m tile (all 16 r). 4096 jobs =
// 1024 blocks x 4 waves, NO barriers.
// lg (log-gate) tile lives in LDS with an XOR-swizzled layout:
//   lg_sem[r][n][m] stored at L[n][r][ m ^ (r&12) ^ (n&12) ]
// -> 34.8KB/block (4 blocks/CU = 16 waves/CU, was 43.5KB/3 blocks), with
// b64-optimal (uniform 4 lanes/bank-pair) access on both write and read.
__global__ __launch_bounds__(256, 4) void gate_score_kernel(
    const float* __restrict__ pe, const float* __restrict__ WGw,
    const float* __restrict__ WGb,
    const __bf16* __restrict__ Kb, const __bf16* __restrict__ Qb,
    _Float16* __restrict__ X) {
  __shared__ alignas(16) _Float16 lg[4][16][17][16];   // [wave][n][r(+pad)][m swz]
  int t = threadIdx.x;
  int l = t & 63, w = t >> 6;
  int job = blockIdx.x * 4 + w;
  int nt = job >> 6, mt = job & 63;
  int n0 = nt * 16, m0 = mt * 16;
  int pr = l & 15;            // A-row / B-col selector
  int kg = (l >> 4) * 8;      // k-offset within frag
  int mq = (l >> 4) << 2;     // D row quad base

  // WG B-frags (fp32 -> bf16), col = r = pr
  bf16x8 wgf[2];
  #pragma unroll
  for (int f = 0; f < 2; f++) {
    const float* wp = WGw + pr * DG + f * 32 + kg;
    float4 a = *(const float4*)wp;
    float4 b = *(const float4*)(wp + 4);
    bf16x8 v;
    v[0] = (__bf16)a.x; v[1] = (__bf16)a.y; v[2] = (__bf16)a.z; v[3] = (__bf16)a.w;
    v[4] = (__bf16)b.x; v[5] = (__bf16)b.y; v[6] = (__bf16)b.z; v[7] = (__bf16)b.w;
    wgf[f] = v;
  }
  float biasr = WGb[pr];

  // ---- gate: 16 n, 2 MFMA each ----
  #pragma unroll 4
  for (int nl = 0; nl < 16; nl++) {
    const float* pp = pe + (((size_t)(n0 + nl) << 10) + m0 + pr) * DG + kg;
    f32x4 acc = {};
    #pragma unroll
    for (int f = 0; f < 2; f++) {
      float4 a = *(const float4*)(pp + f * 32);
      float4 b = *(const float4*)(pp + f * 32 + 4);
      bf16x8 av;
      av[0] = (__bf16)a.x; av[1] = (__bf16)a.y; av[2] = (__bf16)a.z; av[3] = (__bf16)a.w;
      av[4] = (__bf16)b.x; av[5] = (__bf16)b.y; av[6] = (__bf16)b.z; av[7] = (__bf16)b.w;
      acc = __builtin_amdgcn_mfma_f32_16x16x32_bf16(av, wgf[f], acc, 0, 0, 0);
    }
    // D: col = r = pr, row = m-local = mq + q
    f16x4 ov;
    #pragma unroll
    for (int q = 0; q < 4; q++)
      ov[q] = (_Float16)__logf(fmaxf(acc[q] + biasr, 1e-6f));
    // store lg_sem[r=pr][n=nl][m=mq..mq+3] at swizzled slot
    *(f16x4*)&lg[w][nl][pr][mq ^ (pr & 12) ^ (nl & 12)] = ov;
  }

  // ---- score: 16 r, 2 MFMA each; combine with lg; store X ----
  #pragma unroll 4
  for (int r = 0; r < 16; r++) {
    const __bf16* Kr = Kb + (((size_t)r << 10)) * DK;
    const __bf16* Qr = Qb + (((size_t)r << 10)) * DK;
    f32x4 acc = {};
    #pragma unroll
    for (int f = 0; f < 2; f++) {
      bf16x8 qa = *(const bf16x8*)(Qr + (size_t)(m0 + pr) * DK + f * 32 + kg);
      bf16x8 kb = *(const bf16x8*)(Kr + (size_t)(n0 + pr) * DK + f * 32 + kg);
      acc = __builtin_amdgcn_mfma_f32_16x16x32_bf16(qa, kb, acc, 0, 0, 0);
    }
    // D: col = n-local = pr, row = m-local = mq + q
    // read lg_sem[r][n=pr][m=mq..mq+3] from swizzled slot
    f16x4 lgv = *(const f16x4*)&lg[w][pr][r][mq ^ (r & 12) ^ (pr & 12)];
    f16x4 xv;
    #pragma unroll
    for (int q = 0; q < 4; q++)
      xv[q] = (_Float16)(acc[q] * 0.125f + (float)lgv[q]);
    *(f16x4*)(X + ((size_t)r << 20) + ((size_t)(n0 + pr) << 10) + m0 + mq) = xv;
  }
}

// ---------------- K3: per-(r,n) row max and sum-exp over X ----------------
__global__ __launch_bounds__(256) void stats_kernel(
    const _Float16* __restrict__ X, float2* __restrict__ stats) {
  int row = blockIdx.x * 4 + (threadIdx.x >> 6);  // 0..16383 = r*1024+n
  int l = threadIdx.x & 63;
  const f16x8* Sp = (const f16x8*)(X + ((size_t)row << 10) + l * 16);
  f16x8 a = Sp[0], b = Sp[1];
  float v[16];
  float mx = -1e30f;
  #pragma unroll
  for (int i = 0; i < 8; i++) { v[i] = (float)a[i]; v[8 + i] = (float)b[i]; }
  #pragma unroll
  for (int i = 0; i < 16; i++) mx = fmaxf(mx, v[i]);
  #pragma unroll
  for (int off = 32; off >= 1; off >>= 1) mx = fmaxf(mx, __shfl_xor(mx, off, 64));
  float sm = 0.f;
  #pragma unroll
  for (int i = 0; i < 16; i++) sm += __expf(v[i] - mx);
  #pragma unroll
  for (int off = 32; off >= 1; off >>= 1) sm += __shfl_xor(sm, off, 64);
  if (l == 0) stats[row] = make_float2(mx, sm);
}

// ---------------- K4: MFMA PV + residual (1 wave per job, no LDS/sync) ----------------
// Job = (r, 16-row n-tile, 32-col d-half). 2048 wave-jobs = 512 blocks x 4.
// Each wave: full m loop (32 k-steps), A-frag = exp(X-mx) in bf16 built
// in-register, B-frag = Vt[r][d][m] contiguous 16B loads, 2 MFMAs/step.
// exp argument clamped to <=0 (mathematical invariant: X <= row max).
__global__ __launch_bounds__(256) void pv_kernel(
    const _Float16* __restrict__ X, const float2* __restrict__ stats,
    const __bf16* __restrict__ Vt, const float* __restrict__ fa,
    float* __restrict__ out) {
  int t = threadIdx.x;
  int l = t & 63, w = t >> 6;
  int job = blockIdx.x * 4 + w;      // 0..2047
  int dh = job & 1;                  // d-half: 0 -> d 0..31, 1 -> d 32..63
  int jj = job >> 1;                 // 0..1023
  int r = jj >> 6;
  int n0 = (jj & 63) * 16;
  int pr = l & 15;                   // A-row (n-local) / B-col (d-local)
  int kg = (l >> 4) * 8;             // k-chunk within 32-wide window

  float mxl = stats[r * NN + n0 + pr].x;
  const _Float16* Xrow = X + ((size_t)r << 20) + ((size_t)(n0 + pr) << 10);
  const __bf16* V0 = Vt + (size_t)(r * DK + dh * 32) * NN;

  f32x4 acc[2] = {};
  #pragma unroll 2
  for (int k0 = 0; k0 < NN; k0 += 32) {
    f16x8 xv = *(const f16x8*)(Xrow + k0 + kg);
    bf16x8 pa;
    #pragma unroll
    for (int jq = 0; jq < 8; jq++)
      pa[jq] = (__bf16)__expf(fminf((float)xv[jq] - mxl, 0.0f));
    #pragma unroll
    for (int dt = 0; dt < 2; dt++) {
      bf16x8 vb = *(const bf16x8*)(V0 + (size_t)(dt * 16 + pr) * NN + k0 + kg);
      acc[dt] = __builtin_amdgcn_mfma_f32_16x16x32_bf16(pa, vb, acc[dt], 0, 0, 0);
    }
  }

  // D layout: row(n-local) = (l>>4)*4+q, col(d-local) = pr
  #pragma unroll
  for (int q = 0; q < 4; q++) {
    int n = n0 + (l >> 4) * 4 + q;
    float rs = 1.0f / stats[r * NN + n].y;
    #pragma unroll
    for (int dt = 0; dt < 2; dt++) {
      int col = r * DK + dh * 32 + dt * 16 + pr;
      out[(size_t)n * DAPP + col] = acc[dt][q] * rs + fa[(size_t)n * DAPP + col];
    }
  }
}

// ---------------- launch ----------------
extern "C" void kernel_launch(void* const* d_in, const int* in_sizes, int n_in,
                              void* d_out, int out_size, void* d_ws, size_t ws_size,
                              hipStream_t stream) {
  const float* fa  = (const float*)d_in[0];
  const float* pe  = (const float*)d_in[1];
  const float* WGw = (const float*)d_in[2];
  const float* WGb = (const float*)d_in[3];
  const float* WKw = (const float*)d_in[4];
  const float* WKb = (const float*)d_in[5];
  const float* WQw = (const float*)d_in[6];
  const float* WQb = (const float*)d_in[7];
  const float* WVw = (const float*)d_in[8];
  const float* WVb = (const float*)d_in[9];
  float* out = (float*)d_out;

  char* ws = (char*)d_ws;
  __bf16* fab = (__bf16*)(ws + OFF_FAB);
  __bf16* wb  = (__bf16*)(ws + OFF_WB);
  __bf16* Kb  = (__bf16*)(ws + OFF_KB);
  __bf16* Qb  = (__bf16*)(ws + OFF_QB);
  __bf16* Vt  = (__bf16*)(ws + OFF_V);
  _Float16* X = (_Float16*)(ws + OFF_S);
  float2* st  = (float2*)(ws + OFF_ST);

  // K0: cast (4M elems, 8/thread)
  cast_kernel<<<2048, 256, 0, stream>>>(fa, WKw, WQw, WVw, fab, wb);
  // K1: KQV projection (V transposed bf16)
  kqv_kernel<<<768, 256, 0, stream>>>(fab, wb, WKb, WQb, WVb, Kb, Qb, Vt);
  // K2: fused MFMA-gate + scores -> X  (4096 wave-jobs, 1024 blocks)
  gate_score_kernel<<<1024, 256, 0, stream>>>(pe, WGw, WGb, Kb, Qb, X);
  // K3: stats (16384 rows, 4/block)
  stats_kernel<<<4096, 256, 0, stream>>>(X, st);
  // K4: MFMA PV + residual (2048 wave-jobs, 512 blocks)
  pv_kernel<<<512, 256, 0, stream>>>(X, st, Vt, fa, out);
}